// Round 4
// baseline (184.264 us; speedup 1.0000x reference)
//
#include <hip/hip_runtime.h>
#include <hip/hip_bf16.h>

#define BATCH 32
#define SEQ 4096
#define DMODEL 256
#define NCLS 5

typedef short          s8v  __attribute__((ext_vector_type(8)));  // 8 bf16 frag
typedef unsigned short u4v  __attribute__((ext_vector_type(4)));
typedef float          f4v  __attribute__((ext_vector_type(4)));  // C/D frag

// RNE fp32->bf16 via compiler path (fuses to v_cvt_pk_bf16_f32, m240)
__device__ __forceinline__ unsigned short f2bs(float f) {
    __hip_bfloat16 h = __float2bfloat16(f);
    return *reinterpret_cast<unsigned short*>(&h);
}
// DPP row_shr within 16-lane rows, 0-fill (bound_ctrl)
__device__ __forceinline__ float dpp_shr2(float v) {
    return __int_as_float(__builtin_amdgcn_update_dpp(
        0, __float_as_int(v), 0x112, 0xF, 0xF, true));
}
__device__ __forceinline__ float dpp_shr4(float v) {
    return __int_as_float(__builtin_amdgcn_update_dpp(
        0, __float_as_int(v), 0x114, 0xF, 0xF, true));
}
__device__ __forceinline__ float dpp_shr8(float v) {
    return __int_as_float(__builtin_amdgcn_update_dpp(
        0, __float_as_int(v), 0x118, 0xF, 0xF, true));
}
// ds_swizzle BitMode: lane -> lane|14 (broadcast c=7 lane of each parity pair)
__device__ __forceinline__ float swz_or14(float v) {
    return __int_as_float(__builtin_amdgcn_ds_swizzle(
        __float_as_int(v), 0x01DF));
}

// Grid 512 = 256 d x 2 batch-halves; 8 waves/block; ZERO main-loop barriers.
// R3 post-mortem: R1's frag set (3 matrices x 32 regs) put combined
// VGPR+AGPR ~192 -> hard 2 waves/SIMD. This version keeps ONLY MA' in regs;
// CAT/TG frags + cq/hcp C-operands re-read from LDS per group, a^c
// recomputed -> combined <=128 -> 4 waves/SIMD (2 blocks/CU, LDS 47.5KB).
// Wave owns 2 batches x 8 chunks (col m16 -> b_loc=m16&1, c=m16>>1);
// 8 groups of 512 timesteps. x loads go DIRECTLY global->B-frags (x is
// L2-resident; no Xb LDS buffer at all).
// Per group: B: vB[n,col] = MA'[n,j]*x + cq (C-in);
//   scan: 8-chunk Kogge-Stone via dpp row_shr2/4/8 (parity-preserving:
//     i1=v+a*shr2(v); i2=i1+a2*shr4(i1); i3=i2+a4*shr8(i2); e=shr2(i3)=i_{c-1};
//     se = a^c*sig0 + e; sig0' = a^8*sig0 + bcast(i3@c=7) via swz or14);
//   D: y = CAT x Sig + TG x Xb (C-in = Hcp; Dw*x folded into TG diagonal)
//     -> gelu -> per-lane pool -> per-wave shfl reduce -> fused atomic head.
// MFMA 16x16x32 bf16 layouts (verified m89/m91): A[m=lane&15][k=quad*8+j],
// B[k=quad*8+j][n=lane&15], D: col=lane&15, row=quad*4+reg.
__global__ __launch_bounds__(512, 2) void ssm_mfma_kernel(
    const float* __restrict__ x,      // [B, T]
    const float* __restrict__ w_in,   // [D]
    const float* __restrict__ b_in,   // [D]
    const float* __restrict__ A_diag, // [D, 64]
    const float* __restrict__ B_in,   // [D, 64]
    const float* __restrict__ C_out,  // [D, 64]
    const float* __restrict__ D_skip, // [D]
    const float* __restrict__ W_head, // [2D, NCLS]
    const float* __restrict__ b_head, // [NCLS]
    float* __restrict__ out)          // [B, NCLS] (pre-zeroed, atomic accum)
{
    __shared__ __align__(16) unsigned short Sigb[128 * 72];  // 18.4KB; Pow aliases
    __shared__ unsigned short MAb [64 * 72];
    __shared__ unsigned short CATb[64 * 72];
    __shared__ unsigned short TGb [64 * 72];
    __shared__ float Pf[64], Qf[64], Gf[64], Hf[64], HcpS[64], Anf[64], cqS[64];

    float* Pow = (float*)Sigb;   // [65*64] = 16640 B <= 18432 B (setup only)

    const int tid  = threadIdx.x;
    const int lane = tid & 63;
    const int wid  = tid >> 6;
    const int m16  = lane & 15;
    const int q    = lane >> 4;
    const int q4   = q * 4;
    const int q8   = q * 8;
    const int d    = blockIdx.x >> 1;
    const int bh   = blockIdx.x & 1;

    const int pcol = wid * 16 + m16;          // wave-private Sigb row
    const int cch  = m16 >> 1;                // chunk index 0..7
    const bool cc1 = (cch & 1) != 0;
    const bool cc2 = (cch & 2) != 0;
    const bool cc4 = (cch & 4) != 0;

    const float wd = w_in[d], bd = b_in[d];
    const float Dw = D_skip[d] * wd;
    const float Db = D_skip[d] * bd;

    // direct-load geometry: lane (m16,q) -> x[b, g*512 + c*64 + q8 + j]
    const int bglob = bh * 16 + wid * 2 + (m16 & 1);
    const float* xrow = x + bglob * SEQ + cch * 64 + q * 8;

    // issue group-0 loads immediately; setup hides the latency
    float4 xa = ((const float4*)xrow)[0];         // j = q8+0..3
    float4 xb = ((const float4*)xrow)[1];         // j = q8+4..7
    float4 xc = ((const float4*)(xrow + 32))[0];  // j = 32+q8+0..3
    float4 xd = ((const float4*)(xrow + 32))[1];  // j = 32+q8+4..7

    // ---- setup 1: per-n tables + power table (wave 0) ----
    if (tid < 64) {
        const int n = tid;
        const float An = A_diag[d * 64 + n];
        const float CB = B_in[d * 64 + n] * C_out[d * 64 + n];
        Anf[n] = An; Pf[n] = CB * wd; Qf[n] = CB * bd;
        float p = 1.0f;
        for (int m = 0; m <= 64; ++m) { Pow[m * 64 + n] = p; p *= An; }
    }
    __syncthreads();
    // ---- setup 2: G/H = Pow x {P,Q} matvec, 8 threads per row ----
    {
        const int mrow = tid >> 3, p8 = (tid & 7) * 8;
        float g = 0.0f, h = 0.0f;
        #pragma unroll
        for (int jj = 0; jj < 8; ++jj) {
            const float pw = Pow[mrow * 64 + p8 + jj];
            g = fmaf(pw, Pf[p8 + jj], g);
            h = fmaf(pw, Qf[p8 + jj], h);
        }
        g += __shfl_xor(g, 1, 64); g += __shfl_xor(g, 2, 64); g += __shfl_xor(g, 4, 64);
        h += __shfl_xor(h, 1, 64); h += __shfl_xor(h, 2, 64); h += __shfl_xor(h, 4, 64);
        if ((tid & 7) == 0) { Gf[mrow] = g; Hf[mrow] = h; }
    }
    __syncthreads();
    // ---- setup 3: MA'/CAT/TG matrices + Hcp prefix + cq ----
    {
        const int r0 = tid >> 3, c0 = (tid & 7) * 8;
        #pragma unroll
        for (int jj = 0; jj < 8; ++jj) {
            const int j = c0 + jj;
            MAb [r0 * 72 + j] = f2bs(Pf[r0] * Pow[(63 - j) * 64 + r0]);
            CATb[r0 * 72 + j] = f2bs(Pow[(r0 + 1) * 64 + j]);
            TGb [r0 * 72 + j] = (j < r0)  ? f2bs(Gf[r0 - j])
                              : (j == r0) ? f2bs(Gf[0] + Dw)   // Dw*x folded in
                                          : (unsigned short)0;
        }
        if (tid < 64) {
            float v = Hf[tid];
            #pragma unroll
            for (int dl = 1; dl < 64; dl <<= 1) {
                const float t = __shfl(v, (tid - dl) & 63, 64);
                v += (tid >= dl) ? t : 0.0f;
            }
            HcpS[tid] = v + Db;
            const float A64 = Pow[64 * 64 + tid];
            cqS[tid] = Qf[tid] * (1.0f - A64) / (1.0f - Anf[tid]);
        }
    }
    __syncthreads();

    // ---- loop-invariant regs: ONLY MA' fragments (32) + a^64 (16) ----
    s8v aMA[4][2];
    #pragma unroll
    for (int rt = 0; rt < 4; ++rt)
        #pragma unroll
        for (int kb = 0; kb < 2; ++kb)
            aMA[rt][kb] = *(const s8v*)&MAb[(rt * 16 + m16) * 72 + kb * 32 + q8];
    float a64v[4][4], sig0[4][4];
    #pragma unroll
    for (int rt = 0; rt < 4; ++rt)
        #pragma unroll
        for (int r = 0; r < 4; ++r) {
            a64v[rt][r] = Pow[64 * 64 + rt * 16 + q4 + r];   // last Pow read
            sig0[rt][r] = 0.0f;
        }
    __syncthreads();   // Pow reads done before scan overwrites Sigb

    // ---- prologue: pack group-0 B-frags in registers ----
    s8v bx0, bx1;
    bx0[0]=(short)f2bs(xa.x); bx0[1]=(short)f2bs(xa.y);
    bx0[2]=(short)f2bs(xa.z); bx0[3]=(short)f2bs(xa.w);
    bx0[4]=(short)f2bs(xb.x); bx0[5]=(short)f2bs(xb.y);
    bx0[6]=(short)f2bs(xb.z); bx0[7]=(short)f2bs(xb.w);
    bx1[0]=(short)f2bs(xc.x); bx1[1]=(short)f2bs(xc.y);
    bx1[2]=(short)f2bs(xc.z); bx1[3]=(short)f2bs(xc.w);
    bx1[4]=(short)f2bs(xd.x); bx1[5]=(short)f2bs(xd.y);
    bx1[6]=(short)f2bs(xd.z); bx1[7]=(short)f2bs(xd.w);

    float psum = 0.0f, pmax = -1e30f;

    #pragma unroll 1
    for (int g = 0; g < 8; ++g) {
        // issue-early loads for group g+1 (drain covered by whole body)
        float4 ya, yb, yc, yd;
        if (g < 7) {
            const float* xg = xrow + (g + 1) * 512;
            ya = ((const float4*)xg)[0];
            yb = ((const float4*)xg)[1];
            yc = ((const float4*)(xg + 32))[0];
            yd = ((const float4*)(xg + 32))[1];
        }
        // ---- B: vB = cq + MA' x Xb ----
        f4v vB[4];
        #pragma unroll
        for (int rt = 0; rt < 4; ++rt) {
            const f4v cqv = *(const f4v*)&cqS[rt * 16 + q4];
            f4v t = __builtin_amdgcn_mfma_f32_16x16x32_bf16(aMA[rt][0], bx0, cqv, 0, 0, 0);
            vB[rt] = __builtin_amdgcn_mfma_f32_16x16x32_bf16(aMA[rt][1], bx1, t, 0, 0, 0);
        }
        // ---- in-wave 8-chunk scan (parity-preserving DPP Kogge-Stone) ----
        #pragma unroll
        for (int rt = 0; rt < 4; ++rt) {
            u4v sg;
            #pragma unroll
            for (int r = 0; r < 4; ++r) {
                const float a  = a64v[rt][r];
                const float a2 = a * a, a4 = a2 * a2;
                const float v  = vB[rt][r];
                const float i1 = fmaf(a,  dpp_shr2(v),  v);
                const float i2 = fmaf(a2, dpp_shr4(i1), i1);
                const float i3 = fmaf(a4, dpp_shr8(i2), i2);
                const float e  = dpp_shr2(i3);                 // i_{c-1}
                const float acv = (cc1 ? a : 1.0f) * (cc2 ? a2 : 1.0f)
                                * (cc4 ? a4 : 1.0f);           // a^c
                const float se = fmaf(acv, sig0[rt][r], e);
                const float S  = swz_or14(i3);                 // bcast c=7
                sig0[rt][r] = fmaf(a4 * a4, sig0[rt][r], S);   // A^512 advance
                sg[r] = f2bs(se);
            }
            *(u4v*)&Sigb[pcol * 72 + rt * 16 + q4] = sg;
        }
        const s8v bs0 = *(const s8v*)&Sigb[pcol * 72 + q8];
        const s8v bs1 = *(const s8v*)&Sigb[pcol * 72 + 32 + q8];
        // ---- D: y = Hcp + CAT x Sig + TG x Xb -> gelu -> pool ----
        #pragma unroll
        for (int rt = 0; rt < 4; ++rt) {
            const int ro = (rt * 16 + m16) * 72 + q8;
            const f4v hcpv = *(const f4v*)&HcpS[rt * 16 + q4];
            f4v acc = __builtin_amdgcn_mfma_f32_16x16x32_bf16(
                          *(const s8v*)&CATb[ro], bs0, hcpv, 0, 0, 0);
            acc = __builtin_amdgcn_mfma_f32_16x16x32_bf16(
                          *(const s8v*)&CATb[ro + 32], bs1, acc, 0, 0, 0);
            acc = __builtin_amdgcn_mfma_f32_16x16x32_bf16(
                          *(const s8v*)&TGb[ro], bx0, acc, 0, 0, 0);
            acc = __builtin_amdgcn_mfma_f32_16x16x32_bf16(
                          *(const s8v*)&TGb[ro + 32], bx1, acc, 0, 0, 0);
            #pragma unroll
            for (int r = 0; r < 4; ++r) {
                const float yt = acc[r];
                const float y2 = yt * yt;
                const float zn = yt * fmaf(-0.10294272f, y2, -2.30220437f);
                const float h  = yt * __builtin_amdgcn_rcpf(1.0f + exp2f(zn));
                psum += h;
                pmax = fmaxf(pmax, h);
            }
        }
        // ---- rotate prefetch into B-frags for g+1 ----
        if (g < 7) {
            bx0[0]=(short)f2bs(ya.x); bx0[1]=(short)f2bs(ya.y);
            bx0[2]=(short)f2bs(ya.z); bx0[3]=(short)f2bs(ya.w);
            bx0[4]=(short)f2bs(yb.x); bx0[5]=(short)f2bs(yb.y);
            bx0[6]=(short)f2bs(yb.z); bx0[7]=(short)f2bs(yb.w);
            bx1[0]=(short)f2bs(yc.x); bx1[1]=(short)f2bs(yc.y);
            bx1[2]=(short)f2bs(yc.z); bx1[3]=(short)f2bs(yc.w);
            bx1[4]=(short)f2bs(yd.x); bx1[5]=(short)f2bs(yd.y);
            bx1[6]=(short)f2bs(yd.z); bx1[7]=(short)f2bs(yd.w);
        }
    }

    // ---- pool: reduce across lanes sharing parity (b_loc = lane&1) ----
    #pragma unroll
    for (int dl = 2; dl <= 32; dl <<= 1) {
        psum += __shfl_xor(psum, dl, 64);
        pmax  = fmaxf(pmax, __shfl_xor(pmax, dl, 64));
    }
    // ---- fused head: out[b,c] += avg*W[d,c] + max*W[D+d,c] (+bias once) ----
    if (lane < 2) {
        const int bg = bh * 16 + wid * 2 + lane;
        const float s  = psum * (1.0f / SEQ);
        #pragma unroll
        for (int c = 0; c < NCLS; ++c) {
            float contrib = s    * W_head[d * NCLS + c]
                          + pmax * W_head[(DMODEL + d) * NCLS + c];
            if (d == 0) contrib += b_head[c];   // each (b,c) gets bias once
            atomicAdd(&out[bg * NCLS + c], contrib);
        }
    }
}

extern "C" void kernel_launch(void* const* d_in, const int* in_sizes, int n_in,
                              void* d_out, int out_size, void* d_ws, size_t ws_size,
                              hipStream_t stream) {
    const float* x      = (const float*)d_in[0];
    const float* w_in   = (const float*)d_in[1];
    const float* b_in   = (const float*)d_in[2];
    const float* A_diag = (const float*)d_in[3];
    const float* B_in   = (const float*)d_in[4];
    const float* C_out  = (const float*)d_in[5];
    const float* D_skip = (const float*)d_in[6];
    const float* W_head = (const float*)d_in[7];
    const float* b_head = (const float*)d_in[8];
    float* out = (float*)d_out;

    hipMemsetAsync(out, 0, BATCH * NCLS * sizeof(float), stream);
    ssm_mfma_kernel<<<DMODEL * 2, 512, 0, stream>>>(x, w_in, b_in, A_diag, B_in,
                                                    C_out, D_skip, W_head, b_head, out);
}